// Round 4
// baseline (312.895 us; speedup 1.0000x reference)
//
#include <hip/hip_runtime.h>

// Problem constants
#define B 8
#define N 4096
#define C 128
#define C2 256          // K-dim of fused GEMM: [ptl | s]
#define KNN 21          // top-(K+1), drop nearest
#define CAP 15          // per-lane append buffer capacity (slots 0..14)

typedef unsigned long long u64;
typedef unsigned int u32;
typedef unsigned short u16;

typedef __attribute__((ext_vector_type(8))) short bf16x8;
typedef __attribute__((ext_vector_type(4))) float f32x4;

__device__ __forceinline__ float bf2f(u16 u) {
    return __uint_as_float(((u32)u) << 16);
}
__device__ __forceinline__ u16 f2bf(float f) {  // round-to-nearest-even
    u32 x = __float_as_uint(f);
    return (u16)((x + 0x7FFFu + ((x >> 16) & 1u)) >> 16);
}

// ---------------------------------------------------------------------------
// K1: transpose + leaky_relu: points (B,C,N) f32 -> X[b][n][c] (c<128) bf16.
// Also prepacks cand[b][m] = float4(x, y, z, sq_norm) once per point (same
// __fmul_rn/__fadd_rn sequence the KNN staging used inline -> bit-identical).
// ---------------------------------------------------------------------------
__global__ __launch_bounds__(256) void k_transpose_lrelu(
        const float* __restrict__ pts, u16* __restrict__ X,
        const float* __restrict__ xyz, float4* __restrict__ cand) {
    __shared__ u16 tile[32][33];
    int b  = blockIdx.z;
    int c0 = blockIdx.y * 32;
    int n0 = blockIdx.x * 32;
    int tx = threadIdx.x, ty = threadIdx.y;   // 32 x 8

    if (blockIdx.y == 0 && ty == 0) {         // prepack: 32 lanes, 32 points
        int n = n0 + tx;
        const float* xz = xyz + (size_t)b * 3 * N;
        float x = xz[n], y = xz[N + n], z = xz[2 * N + n];
        float sn = __fadd_rn(__fadd_rn(__fmul_rn(x, x), __fmul_rn(y, y)),
                             __fmul_rn(z, z));
        cand[(size_t)b * N + n] = make_float4(x, y, z, sn);
    }

    const float* src = pts + (size_t)b * C * N;
    #pragma unroll
    for (int i = 0; i < 32; i += 8) {
        float v = src[(size_t)(c0 + ty + i) * N + n0 + tx];
        if (v < 0.f) v = __fmul_rn(v, 0.01f);
        tile[ty + i][tx] = f2bf(v);
    }
    __syncthreads();
    u16* dst = X + (size_t)b * N * C2;
    #pragma unroll
    for (int i = 0; i < 32; i += 8) {
        dst[(size_t)(n0 + ty + i) * C2 + (c0 + tx)] = tile[tx][ty + i];
    }
}

// ---------------------------------------------------------------------------
// K2: exact KNN (top-21 by (sq, idx), drop min) + neighbor-feature gather-sum.
// OCCUPANCY RESTRUCTURE: 512 thr = 8 waves (was 4). Grid stays 512 blocks ->
// 2 blocks/CU -> 16 waves/CU = 4 waves/SIMD (was 2). Wave w scans candidates
// [w*512, +512); per-candidate path (distance, sortable-u32 key, kbuf/ibuf
// append, compact, trigger bound 7+8=CAP) is byte-identical to the proven r0
// loop. Merge cascade: waves 0-3 4-way merge -> LA (LDS), then waves 4-7 +
// LA 5-way merge -> win; wave 0 executes both (dynamic ptrs stay in LDS, no
// register-array scratch). Gather splits 8 queries/wave.
// LDS phase A: stg[8][128]f4 16384 | kbuf[15][512]u32 30720 | ibuf[15][512]u16
// 15360 = 62464 B. Phase B overlays: mg4[4][64][21]u64 @16384, LA[64][21]u64
// @0, win[64][21]u16 @10752.
// ---------------------------------------------------------------------------
__global__ __launch_bounds__(512) void k_knn_gather(
        const float4* __restrict__ cand, u16* __restrict__ X) {
    __shared__ __align__(16) char lds[62464];
    float4* stg  = (float4*)lds;                      // [8][128]  16384 B
    u32*    kbuf = (u32*)(lds + 16384);               // [15][512] 30720 B
    u16*    ibuf = (u16*)(lds + 47104);               // [15][512] 15360 B
    u64*    mg4  = (u64*)(lds + 16384);               // [4][64][21] (phase B)
    u64*    la   = (u64*)lds;                         // [64][21]    (phase B)
    u16*    win  = (u16*)(lds + 10752);               // [64][21]    (phase B)

    int tid = threadIdx.x;
    int w = tid >> 6, l = tid & 63;
    int b = blockIdx.y;
    int n0 = blockIdx.x * 64;
    int nq = n0 + l;

    const float4* candb = cand + (size_t)b * N;
    float4 cq = candb[nq];                            // query point (coalesced)
    float qx = cq.x, qy = cq.y, qz = cq.z, snq = cq.w;

    u32 key[KNN], idx[KNN];
    #pragma unroll
    for (int i = 0; i < KNN; ++i) { key[i] = 0xFFFFFFFFu; idx[i] = 0u; }
    int cnt = 0;
    u32 thr = 0xFFFFFFFFu;

    auto compact = [&]() {
        #pragma unroll 1
        for (int i = 0; i < CAP; ++i) {
            if (__ballot(i < cnt) == 0ull) break;
            u32 kv = kbuf[i * 512 + tid];
            u32 iv = ibuf[i * 512 + tid];
            bool ins = (i < cnt) && (kv < key[20]);   // strict: ties keep old
            if (__ballot(ins) != 0ull) {
                key[20] = ins ? kv : key[20];
                idx[20] = ins ? iv : idx[20];
                #pragma unroll
                for (int t = 19; t >= 0; --t) {       // stable bubble (strict >)
                    bool sw = key[t] > key[t + 1];
                    u32 ka = sw ? key[t + 1] : key[t];
                    u32 kz = sw ? key[t] : key[t + 1];
                    u32 ia = sw ? idx[t + 1] : idx[t];
                    u32 iz = sw ? idx[t] : idx[t + 1];
                    key[t] = ka; key[t + 1] = kz;
                    idx[t] = ia; idx[t + 1] = iz;
                }
            }
        }
        cnt = 0;
        thr = key[20];
    };

    float4* mystg = stg + w * 128;

    for (int sc = 0; sc < 4; ++sc) {
        int m0 = w * 512 + sc * 128;
        // stage 128 candidates from prepacked cand (coalesced float4)
        float4 v0 = candb[m0 + l];
        float4 v1 = candb[m0 + l + 64];
        mystg[l]      = v0;
        mystg[l + 64] = v1;
        asm volatile("s_waitcnt lgkmcnt(0)" ::: "memory");
        for (int cc = 0; cc < 128; cc += 8) {
            #pragma unroll
            for (int j = 0; j < 8; ++j) {
                float4 cp = mystg[cc + j];            // wave-broadcast read
                int m = m0 + cc + j;
                float dot = __fadd_rn(__fadd_rn(__fmul_rn(qx, cp.x),
                                                __fmul_rn(qy, cp.y)),
                                      __fmul_rn(qz, cp.z));
                float sq = __fadd_rn(__fsub_rn(snq, __fadd_rn(dot, dot)), cp.w);
                u32 bits = __float_as_uint(sq);
                u32 kb = bits ^ (0x80000000u | (u32)(((int)bits) >> 31));
                kbuf[cnt * 512 + tid] = kb;           // unconditional append
                ibuf[cnt * 512 + tid] = (u16)m;
                cnt += (kb < thr);                    // strict: ties dropped
            }
            if (__ballot(cnt >= 8) != 0ull) compact();  // 7+8 = CAP bound
        }
    }
    compact();

    __syncthreads();                                  // phase-A buffers dead
    if (w < 4) {                                      // park waves 0-3 lists
        #pragma unroll
        for (int j = 0; j < KNN; ++j)
            mg4[(w * 64 + l) * KNN + j] = ((u64)key[j] << 32) | (u64)idx[j];
    }
    __syncthreads();

    if (w == 0) {                                     // 4-way merge -> LA
        int p0 = 0, p1 = 0, p2 = 0, p3 = 0;
        for (int j = 0; j < KNN; ++j) {
            u64 c0 = mg4[(0 * 64 + l) * KNN + p0];
            u64 c1 = mg4[(1 * 64 + l) * KNN + p1];
            u64 c2 = mg4[(2 * 64 + l) * KNN + p2];
            u64 c3 = mg4[(3 * 64 + l) * KNN + p3];
            u64 m01 = c0 < c1 ? c0 : c1; int s01 = c0 < c1 ? 0 : 1;
            u64 m23 = c2 < c3 ? c2 : c3; int s23 = c2 < c3 ? 2 : 3;
            u64 mm = m01 < m23 ? m01 : m23;
            int sel = m01 < m23 ? s01 : s23;
            la[l * KNN + j] = mm;
            p0 += (sel == 0); p1 += (sel == 1); p2 += (sel == 2); p3 += (sel == 3);
        }
    }
    __syncthreads();

    if (w >= 4) {                                     // park waves 4-7 lists
        #pragma unroll
        for (int j = 0; j < KNN; ++j)
            mg4[((w - 4) * 64 + l) * KNN + j] = ((u64)key[j] << 32) | (u64)idx[j];
    }
    __syncthreads();

    if (w == 0) {                                     // 5-way: mg4 x4 + LA -> win
        int p0 = 0, p1 = 0, p2 = 0, p3 = 0, pa = 0;
        for (int j = 0; j < KNN; ++j) {
            u64 c0 = mg4[(0 * 64 + l) * KNN + p0];
            u64 c1 = mg4[(1 * 64 + l) * KNN + p1];
            u64 c2 = mg4[(2 * 64 + l) * KNN + p2];
            u64 c3 = mg4[(3 * 64 + l) * KNN + p3];
            u64 ca = la[l * KNN + pa];
            u64 m01 = c0 < c1 ? c0 : c1; int s01 = c0 < c1 ? 0 : 1;
            u64 m23 = c2 < c3 ? c2 : c3; int s23 = c2 < c3 ? 2 : 3;
            u64 mA = m01 < m23 ? m01 : m23;
            int sel = m01 < m23 ? s01 : s23;
            bool useA = ca < mA;                      // u64 distinct (idx packed)
            u64 mm = useA ? ca : mA;
            win[l * KNN + j] = (u16)(mm & 0xFFFFu);
            pa += useA;
            if (!useA) {
                p0 += (sel == 0); p1 += (sel == 1);
                p2 += (sel == 2); p3 += (sel == 3);
            }
        }
    }
    __syncthreads();

    // gather-sum: wave w handles 8 queries; lane covers channels 2l, 2l+1
    const u16* Xb = X + (size_t)b * N * C2;
    for (int qq = 0; qq < 8; ++qq) {
        int q = w * 8 + qq;
        float f0 = 0.f, f1 = 0.f;
        #pragma unroll
        for (int j = 1; j < KNN; ++j) {               // skip nearest (j=0)
            int m = win[q * KNN + j];
            u32 u2 = *(const u32*)(Xb + (size_t)m * C2 + 2 * l);
            f0 += bf2f((u16)(u2 & 0xFFFFu));
            f1 += bf2f((u16)(u2 >> 16));
        }
        u16* dst = X + ((size_t)b * N + n0 + q) * C2 + 128 + 2 * l;
        *(u32*)dst = ((u32)f2bf(f1) << 16) | (u32)f2bf(f0);
    }
}

// ---------------------------------------------------------------------------
// K3: MFMA GEMM. out[b][o][n] = (W[o][:].X[b][n][:] + bc[o]+20bg[o])/21 + pts.
// Wave tile: 16(o) x 64(n), K=256 = 8 x mfma_f32_16x16x32_bf16 x 4 subtiles.
// XCD-pairing swizzle: the two blocks sharing an nt's 32KB X panel map to
// dispatch ids exactly 8 apart -> same XCD L2. bid -> (bid&7)*128 + (bid>>3).
// C/D map: col=lane&15 (n), row=(lane>>4)*4+reg (o)  [m89-verified]
// ---------------------------------------------------------------------------
__global__ __launch_bounds__(256) void k_gemm_mfma(
        const u16* __restrict__ X, const float* __restrict__ Wc,
        const float* __restrict__ Wg, const float* __restrict__ pts,
        const float* __restrict__ bc, const float* __restrict__ bg,
        float* __restrict__ out) {
    int lb = (blockIdx.x & 7) * 128 + (blockIdx.x >> 3);  // XCD-pairing swizzle
    int wid = lb * 4 + (threadIdx.x >> 6);   // 0..4095
    int lane = threadIdx.x & 63;
    int ot = wid & 7;            // 8 o-tiles of 16
    int nt = wid >> 3;           // 512 n-tiles of 64
    int b  = nt >> 6;            // 64 n-tiles per batch
    int n0 = (nt & 63) * 64;

    int l16 = lane & 15, lq = lane >> 4;
    const u16* Xb = X + (size_t)b * N * C2;
    const u16* bptr0 = Xb + (size_t)(n0 + 0 * 16 + l16) * C2 + lq * 8;
    const u16* bptr1 = Xb + (size_t)(n0 + 1 * 16 + l16) * C2 + lq * 8;
    const u16* bptr2 = Xb + (size_t)(n0 + 2 * 16 + l16) * C2 + lq * 8;
    const u16* bptr3 = Xb + (size_t)(n0 + 3 * 16 + l16) * C2 + lq * 8;
    const float* wrowc = Wc + (size_t)(ot * 16 + l16) * 128 + lq * 8;
    const float* wrowg = Wg + (size_t)(ot * 16 + l16) * 128 + lq * 8;

    f32x4 acc0 = {0.f, 0.f, 0.f, 0.f};
    f32x4 acc1 = {0.f, 0.f, 0.f, 0.f};
    f32x4 acc2 = {0.f, 0.f, 0.f, 0.f};
    f32x4 acc3 = {0.f, 0.f, 0.f, 0.f};
    #pragma unroll
    for (int kk = 0; kk < 8; ++kk) {
        const float* ws = (kk < 4) ? (wrowc + kk * 32) : (wrowg + (kk - 4) * 32);
        float4 wa = *(const float4*)ws;
        float4 wb = *(const float4*)(ws + 4);
        bf16x8 a;
        a[0] = (short)f2bf(wa.x); a[1] = (short)f2bf(wa.y);
        a[2] = (short)f2bf(wa.z); a[3] = (short)f2bf(wa.w);
        a[4] = (short)f2bf(wb.x); a[5] = (short)f2bf(wb.y);
        a[6] = (short)f2bf(wb.z); a[7] = (short)f2bf(wb.w);
        bf16x8 b0 = *(const bf16x8*)(bptr0 + kk * 32);
        bf16x8 b1 = *(const bf16x8*)(bptr1 + kk * 32);
        bf16x8 b2 = *(const bf16x8*)(bptr2 + kk * 32);
        bf16x8 b3 = *(const bf16x8*)(bptr3 + kk * 32);
        acc0 = __builtin_amdgcn_mfma_f32_16x16x32_bf16(a, b0, acc0, 0, 0, 0);
        acc1 = __builtin_amdgcn_mfma_f32_16x16x32_bf16(a, b1, acc1, 0, 0, 0);
        acc2 = __builtin_amdgcn_mfma_f32_16x16x32_bf16(a, b2, acc2, 0, 0, 0);
        acc3 = __builtin_amdgcn_mfma_f32_16x16x32_bf16(a, b3, acc3, 0, 0, 0);
    }

    const float inv21 = 1.0f / 21.0f;
    float bias[4];
    #pragma unroll
    for (int r = 0; r < 4; ++r) {
        int o = ot * 16 + lq * 4 + r;
        bias[r] = bc[o] + 20.f * bg[o];
    }
    const float* pb = pts + (size_t)b * C * N;
    float* ob = out + (size_t)b * C * N;
    f32x4 accs[4] = {acc0, acc1, acc2, acc3};
    #pragma unroll
    for (int t = 0; t < 4; ++t) {
        int n = n0 + t * 16 + l16;
        #pragma unroll
        for (int r = 0; r < 4; ++r) {
            int o = ot * 16 + lq * 4 + r;
            ob[(size_t)o * N + n] =
                (accs[t][r] + bias[r]) * inv21 + pb[(size_t)o * N + n];
        }
    }
}

// ---------------------------------------------------------------------------
extern "C" void kernel_launch(void* const* d_in, const int* in_sizes, int n_in,
                              void* d_out, int out_size, void* d_ws, size_t ws_size,
                              hipStream_t stream) {
    const float* xyz = (const float*)d_in[0];
    const float* pts = (const float*)d_in[1];
    const float* Wc  = (const float*)d_in[2];
    const float* bc  = (const float*)d_in[3];
    const float* Wg  = (const float*)d_in[4];
    const float* bg  = (const float*)d_in[5];
    float* out = (float*)d_out;

    u16* X = (u16*)d_ws;                              // B*N*C2 bf16 = 16 MB
    float4* cand = (float4*)((char*)d_ws +
                             (size_t)B * N * C2 * sizeof(u16));  // +512 KB

    k_transpose_lrelu<<<dim3(N / 32, C / 32, B), dim3(32, 8), 0, stream>>>(
        pts, X, xyz, cand);
    k_knn_gather<<<dim3(N / 64, B), dim3(512), 0, stream>>>(cand, X);
    k_gemm_mfma<<<dim3(1024), dim3(256), 0, stream>>>(X, Wc, Wg, pts, bc, bg, out);
}